// Round 3
// baseline (424.388 us; speedup 1.0000x reference)
//
#include <hip/hip_runtime.h>
#include <stdint.h>

// ---------------------------------------------------------------------------
// Problem: B=2, S=2048, E=64, H=12, D=128, inner=1536
// Pipeline: [rope table] -> [QKV proj + RoPE -> bf16 (Q pre-scaled)] ->
//           [causal flash attn, split-K within block, S^T/O^T dataflow,
//            32x32 MFMA, no-max softmax, + Wo cast in light blocks] ->
//           [output proj]
// ---------------------------------------------------------------------------

typedef short v8s __attribute__((ext_vector_type(8)));    // 8 x bf16
typedef unsigned int v4u __attribute__((ext_vector_type(4)));
typedef float v4f __attribute__((ext_vector_type(4)));
typedef float v16f __attribute__((ext_vector_type(16)));

#define MFMA16(a, b, c) __builtin_amdgcn_mfma_f32_16x16x32_bf16(a, b, c, 0, 0, 0)
#define MFMA32(a, b, c) __builtin_amdgcn_mfma_f32_32x32x16_bf16(a, b, c, 0, 0, 0)

#if __has_builtin(__builtin_amdgcn_exp2f)
#define EXP2(x) __builtin_amdgcn_exp2f(x)
#else
#define EXP2(x) exp2f(x)
#endif

// 1/sqrt(128) * log2(e): folded into Q at projection time
#define SCALE2 (0.08838834764831845f * 1.4426950408889634f)

__device__ __forceinline__ unsigned short f2bf(float f) {
  uint32_t u = __builtin_bit_cast(uint32_t, f);
  u += 0x7FFFu + ((u >> 16) & 1u);   // round-to-nearest-even
  return (unsigned short)(u >> 16);
}

// pack two fp32 -> bf16x2 word (round-half-up) via 2 adds + v_perm_b32
__device__ __forceinline__ uint32_t packbf(float lo, float hi) {
  return __builtin_amdgcn_perm(__builtin_bit_cast(uint32_t, hi) + 0x8000u,
                               __builtin_bit_cast(uint32_t, lo) + 0x8000u,
                               0x07060302u);
}

__device__ __forceinline__ v16f zero16() {
  v16f z;
#pragma unroll
  for (int i = 0; i < 16; ++i) z[i] = 0.f;
  return z;
}

// async global->LDS, 16 B per lane. LDS dst must be wave-uniform base + lane*16.
__device__ __forceinline__ void gl_lds16(const unsigned short* g, unsigned short* l) {
  __builtin_amdgcn_global_load_lds(
      (const __attribute__((address_space(1))) uint32_t*)g,
      (__attribute__((address_space(3))) uint32_t*)l, 16, 0, 0);
}

// ---------------------------------------------------------------------------
// Kernel 0: rope cos/sin table [S=2048][half=64]
// ---------------------------------------------------------------------------
__global__ __launch_bounds__(256) void rope_table(float* __restrict__ cos_t,
                                                  float* __restrict__ sin_t) {
  int idx = blockIdx.x * 256 + threadIdx.x;
  if (idx >= 2048 * 64) return;
  int s = idx >> 6, f = idx & 63;
  // 10000^(-f/64) = exp2(-f * log2(10000)/64)
  float inv = exp2f((float)f * -0.20762050593046014f);
  float ang = (float)s * inv;
  float si, co;
  sincosf(ang, &si, &co);
  cos_t[idx] = co;
  sin_t[idx] = si;
}

// ---------------------------------------------------------------------------
// Kernel 1: QKV projection + RoPE + bf16 cast, LDS-staged coalesced output.
// Q additionally scaled by SCALE2 (rotation commutes with scaling).
// qh/kh: bf16 [B,H,S,D].
// V written FRAGMENT-LINEAR for attn's register-direct PV loads:
//   vtf[bh][kt=tok/64][G=chunk/2 (4)][dt=d/32 (4)][lane=hh*32+(d&31) (64)][8 keys]
//   where chunk=(tok%64)/8, hh=chunk&1, G=chunk>>1.
//   Each (G,dt) block = 64 lanes x 16B contiguous -> one coalesced dwordx4/lane.
// ---------------------------------------------------------------------------
__global__ __launch_bounds__(256) void proj_rope(
    const float* __restrict__ x, const float* __restrict__ Wq,
    const float* __restrict__ Wk, const float* __restrict__ Wv,
    const float* __restrict__ cos_t, const float* __restrict__ sin_t,
    unsigned short* __restrict__ qh, unsigned short* __restrict__ kh,
    unsigned short* __restrict__ vt) {
  const int wave = threadIdx.x >> 6, lane = threadIdx.x & 63;
  const int l16 = lane & 15, quad = lane >> 4;
  const int by = blockIdx.y;
  const int o_base = by * 64 + wave * 16;
  const int mat = o_base / 1536;                    // 0=q 1=k 2=v (block-uniform)
  const int inner0 = o_base % 1536;
  const int d0w = inner0 & 127;
  const float* Wsrc = (mat == 0) ? Wq : ((mat == 1) ? Wk : Wv);
  const float qscale = (mat == 0) ? SCALE2 : 1.0f;

  __shared__ __align__(16) unsigned short Lt[64][72];

  v8s wb[2];
  {
    const float* wr = Wsrc + (size_t)(inner0 + l16) * 64 + quad * 8;
#pragma unroll
    for (int s = 0; s < 2; ++s) {
      float4 a = *(const float4*)(wr + s * 32);
      float4 b = *(const float4*)(wr + s * 32 + 4);
      v8s t;
      t[0] = (short)f2bf(a.x); t[1] = (short)f2bf(a.y);
      t[2] = (short)f2bf(a.z); t[3] = (short)f2bf(a.w);
      t[4] = (short)f2bf(b.x); t[5] = (short)f2bf(b.y);
      t[6] = (short)f2bf(b.z); t[7] = (short)f2bf(b.w);
      wb[s] = t;
    }
  }

  const int d = d0w + l16;
  const int half = d >> 1;

#pragma unroll
  for (int i = 0; i < 4; ++i) {
    const int tok0 = blockIdx.x * 64 + i * 16;
    const float* xr = x + (size_t)(tok0 + l16) * 64 + quad * 8;
    v8s xa[2];
#pragma unroll
    for (int s = 0; s < 2; ++s) {
      float4 a = *(const float4*)(xr + s * 32);
      float4 b = *(const float4*)(xr + s * 32 + 4);
      v8s t;
      t[0] = (short)f2bf(a.x); t[1] = (short)f2bf(a.y);
      t[2] = (short)f2bf(a.z); t[3] = (short)f2bf(a.w);
      t[4] = (short)f2bf(b.x); t[5] = (short)f2bf(b.y);
      t[6] = (short)f2bf(b.z); t[7] = (short)f2bf(b.w);
      xa[s] = t;
    }
    v4f acc = {0.f, 0.f, 0.f, 0.f};
    acc = MFMA16(xa[0], wb[0], acc);
    acc = MFMA16(xa[1], wb[1], acc);

    if (mat < 2) {
#pragma unroll
      for (int r = 0; r < 4; ++r) {
        int sidx = (tok0 + quad * 4 + r) & 2047;
        float val = acc[r];
        float prt = __shfl_xor(val, 1);   // pair partner (d^1), same token
        float co = cos_t[sidx * 64 + half];
        float si = sin_t[sidx * 64 + half];
        float rot = ((d & 1) == 0) ? (val * co - prt * si)
                                   : (prt * si + val * co);
        Lt[i * 16 + quad * 4 + r][wave * 16 + l16] = f2bf(rot * qscale);
      }
    } else {
#pragma unroll
      for (int r = 0; r < 4; ++r)
        Lt[wave * 16 + l16][i * 16 + quad * 4 + r] = f2bf(acc[r]);
    }
  }
  __syncthreads();

  // cooperative b128 coalesced readout
  const int matb = (by * 64) / 1536;
  const int innerb = (by * 64) % 1536;
  const int hb = innerb >> 7;
  const int d0b = innerb & 127;
  const int b = (blockIdx.x * 64) >> 11;
  const int tokbase = (blockIdx.x * 64) & 2047;
#pragma unroll
  for (int jj = 0; jj < 2; ++jj) {
    int cid = jj * 256 + threadIdx.x;
    int outer = cid >> 3, ic = cid & 7;
    v8s val = *(const v8s*)&Lt[outer][ic * 8];
    if (matb < 2) {
      unsigned short* dst = (matb == 0 ? qh : kh) +
          (((size_t)(b * 12 + hb)) * 2048 + tokbase + outer) * 128 + d0b + ic * 8;
      *(v8s*)dst = val;
    } else {
      // fragment-linear vtf store: Lt[outer][ic*8+e] = V^T[d0b+outer][tokbase+ic*8+e]
      const int kt = tokbase >> 6;
      const int G = ic >> 1, hhb = ic & 1;
      const int dd = d0b + outer;
      unsigned short* dst = vt +
          ((((((size_t)(b * 12 + hb)) * 32 + kt) * 4 + G) * 4 + (dd >> 5)) * 64 +
           hhb * 32 + (dd & 31)) * 8;
      *(v8s*)dst = val;
    }
  }
}

// ---------------------------------------------------------------------------
// Kernel 2: causal flash attention, SPLIT-K within block.
//   S^T = K·Q^T  (A=K frag from LDS, B=Q frag in registers)
//   O^T = V^T·P  (A=V^T direct-to-reg from fragment-linear vtf; B=P built
//                 in-register from S^T C-layout via shfl_xor(·,32) swaps)
// v4 restructure: R0-R2 all land at 75-85us regardless of staging/drain
// details -> bottleneck is the SERIAL key-tile chain (qb=15 block = 32
// dependent tiles at ~1 wave/SIMD in the tail; ~5850cy/tile of exposed
// latency). Fix: halve the chain. 512 threads = 8 waves; waves 0-3 (rows
// rg*32) process key-tiles [0,qb+1), waves 4-7 (SAME rows) process
// [qb+1,2qb+2) concurrently. No running max -> partials combine exactly:
// O=Olo+Oup, l=llo+lup (fp32 via LDS, XOR-swizzled float4; no rescale).
// Critical path 32 -> 16 tile-times AND tail runs 2 waves/SIMD.
// LDS: 2 ranges x 2 buffers x 16KB K-tiles = 64KB (+1KB lsum scratch);
// reduce area overlays K tiles (dead after last step). 2 blocks/CU.
// grid (24 bh, 16) qb=15-y heavy-first; bh%8 pins XCD (24%8==0).
// qb==0 blocks (lightest) also cast Wo->bf16 into the dead cos-table region.
// ---------------------------------------------------------------------------
__global__ __launch_bounds__(512, 4) void attn(
    const unsigned short* __restrict__ qh, const unsigned short* __restrict__ kh,
    const unsigned short* __restrict__ vtf, unsigned short* __restrict__ att,
    const float* __restrict__ Wo, unsigned short* __restrict__ wob) {
  const int bh = blockIdx.x;
  const int qb = 15 - (int)blockIdx.y;           // heavy blocks dispatch first
  const int t = threadIdx.x;
  const int lane = t & 63;
  const int l31 = lane & 31, hh = lane >> 5;
  const int w = t >> 6;                          // 8 waves
  const int rg = w & 3, kherd = w >> 2;          // row-group / key-range half
  const int r0w = qb * 128 + rg * 32;
  const int qrow = r0w + l31;
  const int rowmax = r0w + 31;

  const unsigned short* Qb = qh + (size_t)bh * 2048 * 128;
  const unsigned short* Kb = kh + (size_t)bh * 2048 * 128;
  const unsigned short* Vb = vtf + (size_t)bh * 262144;   // 32*4*4*64*8

  // K slots: [range*2 + buf] x 8192 shorts; reduce area overlays after loop.
  __shared__ __align__(16) unsigned short KSH[4 * 8192 + 512];

  // Q fragments (serve as MFMA B-operand): Q[qrow][ks*16 + hh*8 + j]
  v8s qa[8];
  {
    const unsigned short* qr = Qb + (size_t)qrow * 128 + hh * 8;
#pragma unroll
    for (int ks = 0; ks < 8; ++ks) qa[ks] = *(const v8s*)(qr + ks * 16);
  }

  // staging offsets: K swizzle chunk (key, c) holds global d-chunk c^(key&15)
  int offK[2];
#pragma unroll
  for (int i2 = 0; i2 < 2; ++i2) {
    int flat = i2 * 512 + t;
    int kr = flat >> 4, kc = flat & 15;
    offK[i2] = kr * 128 + ((kc ^ (kr & 15)) << 3);
  }
  auto stageT = [&](int ktile, int slot) {
    const unsigned short* kg = Kb + ((size_t)(ktile << 6)) * 128;
    unsigned short* db = &KSH[slot * 8192];
#pragma unroll
    for (int i2 = 0; i2 < 2; ++i2)
      gl_lds16(kg + offK[i2], db + ((i2 * 512 + t) << 3));
  };

  v16f O[4];
#pragma unroll
  for (int i = 0; i < 4; ++i) O[i] = zero16();
  float lsum = 0.f;

  const int NS = qb + 1;
  stageT(0, 0);            // lower range, buf 0
  stageT(qb + 1, 2);       // upper range, buf 0
  asm volatile("s_waitcnt vmcnt(0)" ::: "memory");

  for (int i = 0; i < NS; ++i) {
    __builtin_amdgcn_s_barrier();          // publishes both step-i tiles
    __builtin_amdgcn_sched_barrier(0);
    const int kt = kherd ? (qb + 1 + i) : i;
    const int key0 = kt << 6;
    const bool active = key0 <= rowmax;
    const bool hi = (key0 + 32) <= rowmax;

    // ---- V fragments direct to registers (oldest in FIFO)
    v8s v0a[4], v0b[4], v1a[4], v1b[4];
    if (active) {
      const unsigned short* Vt = Vb + (size_t)kt * 8192;
#pragma unroll
      for (int dt = 0; dt < 4; ++dt)
        v0a[dt] = *(const v8s*)(Vt + ((0 * 4 + dt) * 64 + lane) * 8);
#pragma unroll
      for (int dt = 0; dt < 4; ++dt)
        v0b[dt] = *(const v8s*)(Vt + ((1 * 4 + dt) * 64 + lane) * 8);
      if (hi) {
#pragma unroll
        for (int dt = 0; dt < 4; ++dt)
          v1a[dt] = *(const v8s*)(Vt + ((2 * 4 + dt) * 64 + lane) * 8);
#pragma unroll
        for (int dt = 0; dt < 4; ++dt)
          v1b[dt] = *(const v8s*)(Vt + ((3 * 4 + dt) * 64 + lane) * 8);
      }
    }
    __builtin_amdgcn_sched_barrier(0);

    // ---- next step's K DMA for both ranges
    if (i + 1 < NS) {
      stageT(i + 1, (i + 1) & 1);
      stageT(qb + 2 + i, 2 + ((i + 1) & 1));
    }
    __builtin_amdgcn_sched_barrier(0);

    if (active) {
      const unsigned short* Kl = &KSH[(kherd * 2 + (i & 1)) * 8192];
      const bool mask0 = (key0 + 31) > r0w;
      const bool mask1 = (key0 + 63) > r0w;

      // ---- softpack: S^T half-tile -> packed bf16 P-words + lsum
      auto softpack = [&](const v16f& SS, const v16f& ST, int kh2, bool needmask,
                          uint32_t* W) {
#pragma unroll
        for (int m = 0; m < 8; ++m) {
          float pa = EXP2(SS[2 * m] + ST[2 * m]);
          float pb = EXP2(SS[2 * m + 1] + ST[2 * m + 1]);
          if (needmask) {
            int keyb = key0 + kh2 * 32 + 2 * (m & 1) + 8 * (m >> 1) + 4 * hh;
            pa = (keyb <= qrow) ? pa : 0.f;
            pb = (keyb + 1 <= qrow) ? pb : 0.f;
          }
          lsum += pa + pb;
          W[m] = packbf(pa, pb);
        }
      };
      // ---- pv: build B-operand P frags (word swap across lane^32), mult V^T
      auto pvhalf = [&](const uint32_t* W, int kh2, const v8s* vA, const v8s* vB) {
        uint32_t r0 = __shfl_xor(hh ? W[0] : W[2], 32);
        uint32_t r1 = __shfl_xor(hh ? W[1] : W[3], 32);
        uint32_t r2 = __shfl_xor(hh ? W[4] : W[6], 32);
        uint32_t r3 = __shfl_xor(hh ? W[5] : W[7], 32);
#pragma unroll
        for (int gl = 0; gl < 2; ++gl) {
          const int g = kh2 * 2 + gl;
          if (key0 + g * 16 > rowmax) continue;   // wave-uniform skip
          uint32_t rA = gl ? r2 : r0, rB = gl ? r3 : r1;
          v4u fw;
          fw.x = hh ? rA : W[4 * gl];
          fw.y = hh ? rB : W[4 * gl + 1];
          fw.z = hh ? W[4 * gl + 2] : rA;
          fw.w = hh ? W[4 * gl + 3] : rB;
          v8s pfrag = __builtin_bit_cast(v8s, fw);
          const v8s* vv = gl ? vB : vA;
          __builtin_amdgcn_s_setprio(1);
#pragma unroll
          for (int dt = 0; dt < 4; ++dt) O[dt] = MFMA32(vv[dt], pfrag, O[dt]);
          __builtin_amdgcn_s_setprio(0);
        }
      };

      // ---- S^T = K·Q^T lower 32 keys (two independent 4-deep chains)
      v16f Sa = zero16(), Sb = zero16();
      __builtin_amdgcn_s_setprio(1);
#pragma unroll
      for (int ks = 0; ks < 8; ks += 2) {
        v8s ka0 = *(const v8s*)(
            Kl + ((l31 * 16 + ((2 * ks + hh) ^ (l31 & 15))) << 3));
        v8s ka1 = *(const v8s*)(
            Kl + ((l31 * 16 + ((2 * ks + 2 + hh) ^ (l31 & 15))) << 3));
        Sa = MFMA32(ka0, qa[ks], Sa);
        Sb = MFMA32(ka1, qa[ks + 1], Sb);
      }
      __builtin_amdgcn_s_setprio(0);
      uint32_t W0[8];
      softpack(Sa, Sb, 0, mask0, W0);
      pvhalf(W0, 0, v0a, v0b);

      if (hi) {
        v16f Sc = zero16(), Sd = zero16();
        __builtin_amdgcn_s_setprio(1);
#pragma unroll
        for (int ks = 0; ks < 8; ks += 2) {
          v8s ka0 = *(const v8s*)(
              Kl + (((32 + l31) * 16 + ((2 * ks + hh) ^ (l31 & 15))) << 3));
          v8s ka1 = *(const v8s*)(
              Kl + (((32 + l31) * 16 + ((2 * ks + 2 + hh) ^ (l31 & 15))) << 3));
          Sc = MFMA32(ka0, qa[ks], Sc);
          Sd = MFMA32(ka1, qa[ks + 1], Sd);
        }
        __builtin_amdgcn_s_setprio(0);
        uint32_t W1[8];
        softpack(Sc, Sd, 1, mask1, W1);
        pvhalf(W1, 1, v1a, v1b);
      }
    }
    // staged DMA (and any V loads) must retire before next barrier publishes
    asm volatile("s_waitcnt vmcnt(0)" ::: "memory");
  }

  // ---- split-K reduce: upper waves dump (O, lsum) fp32 to LDS (overlays K)
  __syncthreads();                        // all K reads done; LDS reusable
  float* Ored = (float*)KSH;              // [rg][l31][128] XOR-swizzled
  float* lred = (float*)(KSH + 32768);    // [rg][lane]
  if (kherd == 1) {
    float* baseO = Ored + rg * 4096 + l31 * 128;
#pragma unroll
    for (int dt = 0; dt < 4; ++dt)
#pragma unroll
      for (int pr = 0; pr < 4; ++pr) {
        float4 v;
        v.x = O[dt][4 * pr + 0]; v.y = O[dt][4 * pr + 1];
        v.z = O[dt][4 * pr + 2]; v.w = O[dt][4 * pr + 3];
        *(float4*)(baseO + dt * 32 + (((2 * pr + hh) ^ (l31 & 7)) << 2)) = v;
      }
    lred[rg * 64 + lane] = lsum;
  }
  __syncthreads();
  if (kherd == 0) {
    const float lt = lsum + lred[rg * 64 + lane];
    const float tot = lt + __shfl_xor(lt, 32);
    const float inv = 1.0f / tot;
    const int b = bh / 12, hq = bh % 12;
    unsigned short* arow = att + ((size_t)b * 2048 + qrow) * 1536 + hq * 128;
    const float* baseO = Ored + rg * 4096 + l31 * 128;
#pragma unroll
    for (int dt = 0; dt < 4; ++dt) {
#pragma unroll
      for (int pr = 0; pr < 4; ++pr) {
        float4 v = *(const float4*)(
            baseO + dt * 32 + (((2 * pr + hh) ^ (l31 & 7)) << 2));
        float a0 = (O[dt][4 * pr + 0] + v.x) * inv;
        float a1 = (O[dt][4 * pr + 1] + v.y) * inv;
        float a2 = (O[dt][4 * pr + 2] + v.z) * inv;
        float a3 = (O[dt][4 * pr + 3] + v.w) * inv;
        uint2 uu;
        uu.x = packbf(a0, a1);
        uu.y = packbf(a2, a3);
        *(uint2*)(arow + dt * 32 + 8 * pr + 4 * hh) = uu;
      }
    }
  }

  // ---- lightest blocks also cast Wo -> bf16 (cos table region is dead now)
  if (qb == 0) {
    const int base = bh * 4096;
#pragma unroll
    for (int i = 0; i < 8; ++i)
      wob[base + i * 512 + t] = f2bf(Wo[base + i * 512 + t]);
  }
}

// ---------------------------------------------------------------------------
// Kernel 3: output projection out[tok][e] = sum_i att[tok][i] * Wob[e][i]
// ---------------------------------------------------------------------------
__global__ __launch_bounds__(256) void outproj(
    const unsigned short* __restrict__ att, const unsigned short* __restrict__ wob,
    float* __restrict__ out) {
  const int wave = threadIdx.x >> 6, lane = threadIdx.x & 63;
  const int l16 = lane & 15, quad = lane >> 4;
  const int tok0 = blockIdx.x * 16;
  const int e0 = wave * 16;

  v4f acc0 = {0.f, 0.f, 0.f, 0.f}, acc1 = {0.f, 0.f, 0.f, 0.f};
  const unsigned short* ar = att + (size_t)(tok0 + l16) * 1536 + quad * 8;
  const unsigned short* wr = wob + (size_t)(e0 + l16) * 1536 + quad * 8;
#pragma unroll 4
  for (int s = 0; s < 24; ++s) {
    v8s a0 = *(const v8s*)(ar + (2 * s) * 32);
    v8s b0 = *(const v8s*)(wr + (2 * s) * 32);
    v8s a1 = *(const v8s*)(ar + (2 * s + 1) * 32);
    v8s b1 = *(const v8s*)(wr + (2 * s + 1) * 32);
    acc0 = MFMA16(a0, b0, acc0);
    acc1 = MFMA16(a1, b1, acc1);
  }
#pragma unroll
  for (int r = 0; r < 4; ++r)
    out[(size_t)(tok0 + quad * 4 + r) * 64 + e0 + l16] = acc0[r] + acc1[r];
}

// ---------------------------------------------------------------------------
extern "C" void kernel_launch(void* const* d_in, const int* in_sizes, int n_in,
                              void* d_out, int out_size, void* d_ws,
                              size_t ws_size, hipStream_t stream) {
  const float* q  = (const float*)d_in[0];
  const float* Wq = (const float*)d_in[1];
  const float* Wk = (const float*)d_in[2];
  const float* Wv = (const float*)d_in[3];
  const float* Wo = (const float*)d_in[4];
  float* out = (float*)d_out;

  // workspace layout (bytes):
  //   qh  bf16 [2,12,2048,128]  @ 0           (Q pre-scaled by SCALE2)
  //   kh  bf16 [2,12,2048,128]  @ 12582912
  //   vtf bf16 [24][32][4][4][64][8] @ 25165824   (fragment-linear V)
  //   att bf16 [2,2048,1536]    @ 37748736
  //   cos_t f32 [2048,64]       @ 50331648  (dead after proj_rope; attn's
  //        qb==0 blocks overwrite with Wo bf16 = wob, read by outproj)
  //   sin_t f32 [2048,64]       @ 50855936   (total 51380224)
  unsigned short* ws = (unsigned short*)d_ws;
  unsigned short* qh  = ws;
  unsigned short* kh  = ws + 6291456;
  unsigned short* vtf = ws + 12582912;
  unsigned short* att = ws + 18874368;
  float* cos_t = (float*)((char*)d_ws + 50331648);
  float* sin_t = cos_t + 131072;
  unsigned short* wob = (unsigned short*)cos_t;   // reuse after proj_rope

  rope_table<<<512, 256, 0, stream>>>(cos_t, sin_t);
  proj_rope<<<dim3(64, 72), 256, 0, stream>>>(q, Wq, Wk, Wv, cos_t, sin_t,
                                              qh, kh, vtf);
  attn<<<dim3(24, 16), 512, 0, stream>>>(qh, kh, vtf, att, Wo, wob);
  outproj<<<256, 256, 0, stream>>>(att, wob, out);
}

// Round 4
// 184.029 us; speedup vs baseline: 2.3061x; 2.3061x over previous
//
#include <hip/hip_runtime.h>
#include <stdint.h>

// ---------------------------------------------------------------------------
// Problem: B=2, S=2048, E=64, H=12, D=128, inner=1536
// Pipeline: [rope table] -> [QKV proj + RoPE -> bf16 (Q pre-scaled)] ->
//           [causal flash attn, split-K within block, S^T/O^T dataflow,
//            32x32 MFMA, no-max softmax, + Wo cast in light blocks] ->
//           [output proj]
// ---------------------------------------------------------------------------

typedef short v8s __attribute__((ext_vector_type(8)));    // 8 x bf16
typedef unsigned int v4u __attribute__((ext_vector_type(4)));
typedef float v4f __attribute__((ext_vector_type(4)));
typedef float v16f __attribute__((ext_vector_type(16)));

#define MFMA16(a, b, c) __builtin_amdgcn_mfma_f32_16x16x32_bf16(a, b, c, 0, 0, 0)
#define MFMA32(a, b, c) __builtin_amdgcn_mfma_f32_32x32x16_bf16(a, b, c, 0, 0, 0)

#if __has_builtin(__builtin_amdgcn_exp2f)
#define EXP2(x) __builtin_amdgcn_exp2f(x)
#else
#define EXP2(x) exp2f(x)
#endif

// 1/sqrt(128) * log2(e): folded into Q at projection time
#define SCALE2 (0.08838834764831845f * 1.4426950408889634f)

__device__ __forceinline__ unsigned short f2bf(float f) {
  uint32_t u = __builtin_bit_cast(uint32_t, f);
  u += 0x7FFFu + ((u >> 16) & 1u);   // round-to-nearest-even
  return (unsigned short)(u >> 16);
}

// pack two fp32 -> bf16x2 word (round-half-up) via 2 adds + v_perm_b32
__device__ __forceinline__ uint32_t packbf(float lo, float hi) {
  return __builtin_amdgcn_perm(__builtin_bit_cast(uint32_t, hi) + 0x8000u,
                               __builtin_bit_cast(uint32_t, lo) + 0x8000u,
                               0x07060302u);
}

__device__ __forceinline__ v16f zero16() {
  v16f z;
#pragma unroll
  for (int i = 0; i < 16; ++i) z[i] = 0.f;
  return z;
}

// async global->LDS, 16 B per lane. LDS dst must be wave-uniform base + lane*16.
__device__ __forceinline__ void gl_lds16(const unsigned short* g, unsigned short* l) {
  __builtin_amdgcn_global_load_lds(
      (const __attribute__((address_space(1))) uint32_t*)g,
      (__attribute__((address_space(3))) uint32_t*)l, 16, 0, 0);
}

// ---------------------------------------------------------------------------
// Kernel 0: rope cos/sin table [S=2048][half=64]
// ---------------------------------------------------------------------------
__global__ __launch_bounds__(256) void rope_table(float* __restrict__ cos_t,
                                                  float* __restrict__ sin_t) {
  int idx = blockIdx.x * 256 + threadIdx.x;
  if (idx >= 2048 * 64) return;
  int s = idx >> 6, f = idx & 63;
  // 10000^(-f/64) = exp2(-f * log2(10000)/64)
  float inv = exp2f((float)f * -0.20762050593046014f);
  float ang = (float)s * inv;
  float si, co;
  sincosf(ang, &si, &co);
  cos_t[idx] = co;
  sin_t[idx] = si;
}

// ---------------------------------------------------------------------------
// Kernel 1: QKV projection + RoPE + bf16 cast, LDS-staged coalesced output.
// Q additionally scaled by SCALE2 (rotation commutes with scaling).
// qh/kh: bf16 [B,H,S,D].
// V written FRAGMENT-LINEAR for attn's register-direct PV loads:
//   vtf[bh][kt=tok/64][G=chunk/2 (4)][dt=d/32 (4)][lane=hh*32+(d&31) (64)][8 keys]
//   where chunk=(tok%64)/8, hh=chunk&1, G=chunk>>1.
//   Each (G,dt) block = 64 lanes x 16B contiguous -> one coalesced dwordx4/lane.
// ---------------------------------------------------------------------------
__global__ __launch_bounds__(256) void proj_rope(
    const float* __restrict__ x, const float* __restrict__ Wq,
    const float* __restrict__ Wk, const float* __restrict__ Wv,
    const float* __restrict__ cos_t, const float* __restrict__ sin_t,
    unsigned short* __restrict__ qh, unsigned short* __restrict__ kh,
    unsigned short* __restrict__ vt) {
  const int wave = threadIdx.x >> 6, lane = threadIdx.x & 63;
  const int l16 = lane & 15, quad = lane >> 4;
  const int by = blockIdx.y;
  const int o_base = by * 64 + wave * 16;
  const int mat = o_base / 1536;                    // 0=q 1=k 2=v (block-uniform)
  const int inner0 = o_base % 1536;
  const int d0w = inner0 & 127;
  const float* Wsrc = (mat == 0) ? Wq : ((mat == 1) ? Wk : Wv);
  const float qscale = (mat == 0) ? SCALE2 : 1.0f;

  __shared__ __align__(16) unsigned short Lt[64][72];

  v8s wb[2];
  {
    const float* wr = Wsrc + (size_t)(inner0 + l16) * 64 + quad * 8;
#pragma unroll
    for (int s = 0; s < 2; ++s) {
      float4 a = *(const float4*)(wr + s * 32);
      float4 b = *(const float4*)(wr + s * 32 + 4);
      v8s t;
      t[0] = (short)f2bf(a.x); t[1] = (short)f2bf(a.y);
      t[2] = (short)f2bf(a.z); t[3] = (short)f2bf(a.w);
      t[4] = (short)f2bf(b.x); t[5] = (short)f2bf(b.y);
      t[6] = (short)f2bf(b.z); t[7] = (short)f2bf(b.w);
      wb[s] = t;
    }
  }

  const int d = d0w + l16;
  const int half = d >> 1;

#pragma unroll
  for (int i = 0; i < 4; ++i) {
    const int tok0 = blockIdx.x * 64 + i * 16;
    const float* xr = x + (size_t)(tok0 + l16) * 64 + quad * 8;
    v8s xa[2];
#pragma unroll
    for (int s = 0; s < 2; ++s) {
      float4 a = *(const float4*)(xr + s * 32);
      float4 b = *(const float4*)(xr + s * 32 + 4);
      v8s t;
      t[0] = (short)f2bf(a.x); t[1] = (short)f2bf(a.y);
      t[2] = (short)f2bf(a.z); t[3] = (short)f2bf(a.w);
      t[4] = (short)f2bf(b.x); t[5] = (short)f2bf(b.y);
      t[6] = (short)f2bf(b.z); t[7] = (short)f2bf(b.w);
      xa[s] = t;
    }
    v4f acc = {0.f, 0.f, 0.f, 0.f};
    acc = MFMA16(xa[0], wb[0], acc);
    acc = MFMA16(xa[1], wb[1], acc);

    if (mat < 2) {
#pragma unroll
      for (int r = 0; r < 4; ++r) {
        int sidx = (tok0 + quad * 4 + r) & 2047;
        float val = acc[r];
        float prt = __shfl_xor(val, 1);   // pair partner (d^1), same token
        float co = cos_t[sidx * 64 + half];
        float si = sin_t[sidx * 64 + half];
        float rot = ((d & 1) == 0) ? (val * co - prt * si)
                                   : (prt * si + val * co);
        Lt[i * 16 + quad * 4 + r][wave * 16 + l16] = f2bf(rot * qscale);
      }
    } else {
#pragma unroll
      for (int r = 0; r < 4; ++r)
        Lt[wave * 16 + l16][i * 16 + quad * 4 + r] = f2bf(acc[r]);
    }
  }
  __syncthreads();

  // cooperative b128 coalesced readout
  const int matb = (by * 64) / 1536;
  const int innerb = (by * 64) % 1536;
  const int hb = innerb >> 7;
  const int d0b = innerb & 127;
  const int b = (blockIdx.x * 64) >> 11;
  const int tokbase = (blockIdx.x * 64) & 2047;
#pragma unroll
  for (int jj = 0; jj < 2; ++jj) {
    int cid = jj * 256 + threadIdx.x;
    int outer = cid >> 3, ic = cid & 7;
    v8s val = *(const v8s*)&Lt[outer][ic * 8];
    if (matb < 2) {
      unsigned short* dst = (matb == 0 ? qh : kh) +
          (((size_t)(b * 12 + hb)) * 2048 + tokbase + outer) * 128 + d0b + ic * 8;
      *(v8s*)dst = val;
    } else {
      // fragment-linear vtf store: Lt[outer][ic*8+e] = V^T[d0b+outer][tokbase+ic*8+e]
      const int kt = tokbase >> 6;
      const int G = ic >> 1, hhb = ic & 1;
      const int dd = d0b + outer;
      unsigned short* dst = vt +
          ((((((size_t)(b * 12 + hb)) * 32 + kt) * 4 + G) * 4 + (dd >> 5)) * 64 +
           hhb * 32 + (dd & 31)) * 8;
      *(v8s*)dst = val;
    }
  }
}

// ---------------------------------------------------------------------------
// Kernel 2: causal flash attention, SPLIT-K within block (spill-fixed).
//   S^T = K·Q^T  (A=K frag from LDS, B=Q frag in registers)
//   O^T = V^T·P  (A=V^T direct-to-reg from fragment-linear vtf; B=P built
//                 in-register from S^T C-layout via shfl_xor(·,32) swaps)
// R3 post-mortem: the split-K structure was right but __launch_bounds__(512,4)
// capped VGPR at 128 < the ~150 natural footprint -> O spilled to scratch
// (WRITE_SIZE 369MB, 300us). Fix: (512,2) -> 256 cap (R2's identical per-wave
// structure lands at 120 naturally); LDS trimmed to EXACTLY 64KB (4x16KB K
// slots, lsum exchange moved into a 4-phase epilogue reduce) -> 2 blocks/CU
// when VGPR<=128.
// Structure: 512 thr = 8 waves; waves 0-3 (rows rg*32) process key-tiles
// [0,qb+1), waves 4-7 (SAME rows) process [qb+1,2qb+2) concurrently. No
// running max -> partials combine exactly: O=Olo+Oup, l=llo+lup (fp32 via
// LDS). Critical path 32 -> 16 tile-times AND tail runs >=2 waves/SIMD.
// grid (24 bh, 16) qb=15-y heavy-first; bh%8 pins XCD (24%8==0).
// qb==0 blocks (lightest) also cast Wo->bf16 into the dead cos-table region.
// ---------------------------------------------------------------------------
__global__ __launch_bounds__(512, 2) void attn(
    const unsigned short* __restrict__ qh, const unsigned short* __restrict__ kh,
    const unsigned short* __restrict__ vtf, unsigned short* __restrict__ att,
    const float* __restrict__ Wo, unsigned short* __restrict__ wob) {
  const int bh = blockIdx.x;
  const int qb = 15 - (int)blockIdx.y;           // heavy blocks dispatch first
  const int t = threadIdx.x;
  const int lane = t & 63;
  const int l31 = lane & 31, hh = lane >> 5;
  const int w = t >> 6;                          // 8 waves
  const int rg = w & 3, kherd = w >> 2;          // row-group / key-range half
  const int r0w = qb * 128 + rg * 32;
  const int qrow = r0w + l31;
  const int rowmax = r0w + 31;

  const unsigned short* Qb = qh + (size_t)bh * 2048 * 128;
  const unsigned short* Kb = kh + (size_t)bh * 2048 * 128;
  const unsigned short* Vb = vtf + (size_t)bh * 262144;   // 32*4*4*64*8

  // K slots: [range*2 + buf] x 8192 shorts = 64KB exactly.
  // Epilogue reduce overlays this area (phased; no extra LDS).
  __shared__ __align__(16) unsigned short KSH[4 * 8192];

  // Q fragments (serve as MFMA B-operand): Q[qrow][ks*16 + hh*8 + j]
  v8s qa[8];
  {
    const unsigned short* qr = Qb + (size_t)qrow * 128 + hh * 8;
#pragma unroll
    for (int ks = 0; ks < 8; ++ks) qa[ks] = *(const v8s*)(qr + ks * 16);
  }

  // staging offsets: K swizzle chunk (key, c) holds global d-chunk c^(key&15)
  int offK[2];
#pragma unroll
  for (int i2 = 0; i2 < 2; ++i2) {
    int flat = i2 * 512 + t;
    int kr = flat >> 4, kc = flat & 15;
    offK[i2] = kr * 128 + ((kc ^ (kr & 15)) << 3);
  }
  auto stageT = [&](int ktile, int slot) {
    const unsigned short* kg = Kb + ((size_t)(ktile << 6)) * 128;
    unsigned short* db = &KSH[slot * 8192];
#pragma unroll
    for (int i2 = 0; i2 < 2; ++i2)
      gl_lds16(kg + offK[i2], db + ((i2 * 512 + t) << 3));
  };

  v16f O[4];
#pragma unroll
  for (int i = 0; i < 4; ++i) O[i] = zero16();
  float lsum = 0.f;

  const int NS = qb + 1;
  stageT(0, 0);            // lower range, buf 0
  stageT(qb + 1, 2);       // upper range, buf 0
  asm volatile("s_waitcnt vmcnt(0)" ::: "memory");

  for (int i = 0; i < NS; ++i) {
    __builtin_amdgcn_s_barrier();          // publishes both step-i tiles
    __builtin_amdgcn_sched_barrier(0);
    const int kt = kherd ? (qb + 1 + i) : i;
    const int key0 = kt << 6;
    const bool active = key0 <= rowmax;
    const bool hi = (key0 + 32) <= rowmax;

    // ---- V fragments direct to registers (oldest in FIFO)
    v8s v0a[4], v0b[4], v1a[4], v1b[4];
    if (active) {
      const unsigned short* Vt = Vb + (size_t)kt * 8192;
#pragma unroll
      for (int dt = 0; dt < 4; ++dt)
        v0a[dt] = *(const v8s*)(Vt + ((0 * 4 + dt) * 64 + lane) * 8);
#pragma unroll
      for (int dt = 0; dt < 4; ++dt)
        v0b[dt] = *(const v8s*)(Vt + ((1 * 4 + dt) * 64 + lane) * 8);
      if (hi) {
#pragma unroll
        for (int dt = 0; dt < 4; ++dt)
          v1a[dt] = *(const v8s*)(Vt + ((2 * 4 + dt) * 64 + lane) * 8);
#pragma unroll
        for (int dt = 0; dt < 4; ++dt)
          v1b[dt] = *(const v8s*)(Vt + ((3 * 4 + dt) * 64 + lane) * 8);
      }
    }
    __builtin_amdgcn_sched_barrier(0);

    // ---- next step's K DMA for both ranges
    if (i + 1 < NS) {
      stageT(i + 1, (i + 1) & 1);
      stageT(qb + 2 + i, 2 + ((i + 1) & 1));
    }
    __builtin_amdgcn_sched_barrier(0);

    if (active) {
      const unsigned short* Kl = &KSH[(kherd * 2 + (i & 1)) * 8192];
      const bool mask0 = (key0 + 31) > r0w;
      const bool mask1 = (key0 + 63) > r0w;

      // ---- softpack: S^T half-tile -> packed bf16 P-words + lsum
      auto softpack = [&](const v16f& SS, const v16f& ST, int kh2, bool needmask,
                          uint32_t* W) {
#pragma unroll
        for (int m = 0; m < 8; ++m) {
          float pa = EXP2(SS[2 * m] + ST[2 * m]);
          float pb = EXP2(SS[2 * m + 1] + ST[2 * m + 1]);
          if (needmask) {
            int keyb = key0 + kh2 * 32 + 2 * (m & 1) + 8 * (m >> 1) + 4 * hh;
            pa = (keyb <= qrow) ? pa : 0.f;
            pb = (keyb + 1 <= qrow) ? pb : 0.f;
          }
          lsum += pa + pb;
          W[m] = packbf(pa, pb);
        }
      };
      // ---- pv: build B-operand P frags (word swap across lane^32), mult V^T
      auto pvhalf = [&](const uint32_t* W, int kh2, const v8s* vA, const v8s* vB) {
        uint32_t r0 = __shfl_xor(hh ? W[0] : W[2], 32);
        uint32_t r1 = __shfl_xor(hh ? W[1] : W[3], 32);
        uint32_t r2 = __shfl_xor(hh ? W[4] : W[6], 32);
        uint32_t r3 = __shfl_xor(hh ? W[5] : W[7], 32);
#pragma unroll
        for (int gl = 0; gl < 2; ++gl) {
          const int g = kh2 * 2 + gl;
          if (key0 + g * 16 > rowmax) continue;   // wave-uniform skip
          uint32_t rA = gl ? r2 : r0, rB = gl ? r3 : r1;
          v4u fw;
          fw.x = hh ? rA : W[4 * gl];
          fw.y = hh ? rB : W[4 * gl + 1];
          fw.z = hh ? W[4 * gl + 2] : rA;
          fw.w = hh ? W[4 * gl + 3] : rB;
          v8s pfrag = __builtin_bit_cast(v8s, fw);
          const v8s* vv = gl ? vB : vA;
          __builtin_amdgcn_s_setprio(1);
#pragma unroll
          for (int dt = 0; dt < 4; ++dt) O[dt] = MFMA32(vv[dt], pfrag, O[dt]);
          __builtin_amdgcn_s_setprio(0);
        }
      };

      // ---- S^T = K·Q^T lower 32 keys (two independent 4-deep chains)
      v16f Sa = zero16(), Sb = zero16();
      __builtin_amdgcn_s_setprio(1);
#pragma unroll
      for (int ks = 0; ks < 8; ks += 2) {
        v8s ka0 = *(const v8s*)(
            Kl + ((l31 * 16 + ((2 * ks + hh) ^ (l31 & 15))) << 3));
        v8s ka1 = *(const v8s*)(
            Kl + ((l31 * 16 + ((2 * ks + 2 + hh) ^ (l31 & 15))) << 3));
        Sa = MFMA32(ka0, qa[ks], Sa);
        Sb = MFMA32(ka1, qa[ks + 1], Sb);
      }
      __builtin_amdgcn_s_setprio(0);
      uint32_t W0[8];
      softpack(Sa, Sb, 0, mask0, W0);
      pvhalf(W0, 0, v0a, v0b);

      if (hi) {
        v16f Sc = zero16(), Sd = zero16();
        __builtin_amdgcn_s_setprio(1);
#pragma unroll
        for (int ks = 0; ks < 8; ks += 2) {
          v8s ka0 = *(const v8s*)(
              Kl + (((32 + l31) * 16 + ((2 * ks + hh) ^ (l31 & 15))) << 3));
          v8s ka1 = *(const v8s*)(
              Kl + (((32 + l31) * 16 + ((2 * ks + 2 + hh) ^ (l31 & 15))) << 3));
          Sc = MFMA32(ka0, qa[ks], Sc);
          Sd = MFMA32(ka1, qa[ks + 1], Sd);
        }
        __builtin_amdgcn_s_setprio(0);
        uint32_t W1[8];
        softpack(Sc, Sd, 1, mask1, W1);
        pvhalf(W1, 1, v1a, v1b);
      }
    }
    // staged DMA (and any V loads) must retire before next barrier publishes
    asm volatile("s_waitcnt vmcnt(0)" ::: "memory");
  }

  // ---- split-K reduce, 4 phases overlaying the 64KB K area:
  //   (1) upper waves dump O fp32 (XOR-swizzled float4), (2) lower accumulate
  //   into registers, (3) upper dump lsum (first 1KB, already consumed),
  //   (4) lower normalize + store att.
  __syncthreads();                        // all K reads done; LDS reusable
  float* Ored = (float*)KSH;              // [rg][l31][128] XOR-swizzled
  if (kherd == 1) {
    float* baseO = Ored + rg * 4096 + l31 * 128;
#pragma unroll
    for (int dt = 0; dt < 4; ++dt)
#pragma unroll
      for (int pr = 0; pr < 4; ++pr) {
        float4 v;
        v.x = O[dt][4 * pr + 0]; v.y = O[dt][4 * pr + 1];
        v.z = O[dt][4 * pr + 2]; v.w = O[dt][4 * pr + 3];
        *(float4*)(baseO + dt * 32 + (((2 * pr + hh) ^ (l31 & 7)) << 2)) = v;
      }
  }
  __syncthreads();
  if (kherd == 0) {
    const float* baseO = Ored + rg * 4096 + l31 * 128;
#pragma unroll
    for (int dt = 0; dt < 4; ++dt)
#pragma unroll
      for (int pr = 0; pr < 4; ++pr) {
        float4 v = *(const float4*)(
            baseO + dt * 32 + (((2 * pr + hh) ^ (l31 & 7)) << 2));
        O[dt][4 * pr + 0] += v.x;
        O[dt][4 * pr + 1] += v.y;
        O[dt][4 * pr + 2] += v.z;
        O[dt][4 * pr + 3] += v.w;
      }
  }
  __syncthreads();
  if (kherd == 1) Ored[rg * 64 + lane] = lsum;
  __syncthreads();
  if (kherd == 0) {
    const float lt = lsum + Ored[rg * 64 + lane];
    const float tot = lt + __shfl_xor(lt, 32);
    const float inv = 1.0f / tot;
    const int b = bh / 12, hq = bh % 12;
    unsigned short* arow = att + ((size_t)b * 2048 + qrow) * 1536 + hq * 128;
#pragma unroll
    for (int dt = 0; dt < 4; ++dt) {
#pragma unroll
      for (int pr = 0; pr < 4; ++pr) {
        float a0 = O[dt][4 * pr + 0] * inv;
        float a1 = O[dt][4 * pr + 1] * inv;
        float a2 = O[dt][4 * pr + 2] * inv;
        float a3 = O[dt][4 * pr + 3] * inv;
        uint2 uu;
        uu.x = packbf(a0, a1);
        uu.y = packbf(a2, a3);
        *(uint2*)(arow + dt * 32 + 8 * pr + 4 * hh) = uu;
      }
    }
  }

  // ---- lightest blocks also cast Wo -> bf16 (cos table region is dead now)
  if (qb == 0) {
    const int base = bh * 4096;
#pragma unroll
    for (int i = 0; i < 8; ++i)
      wob[base + i * 512 + t] = f2bf(Wo[base + i * 512 + t]);
  }
}

// ---------------------------------------------------------------------------
// Kernel 3: output projection out[tok][e] = sum_i att[tok][i] * Wob[e][i]
// ---------------------------------------------------------------------------
__global__ __launch_bounds__(256) void outproj(
    const unsigned short* __restrict__ att, const unsigned short* __restrict__ wob,
    float* __restrict__ out) {
  const int wave = threadIdx.x >> 6, lane = threadIdx.x & 63;
  const int l16 = lane & 15, quad = lane >> 4;
  const int tok0 = blockIdx.x * 16;
  const int e0 = wave * 16;

  v4f acc0 = {0.f, 0.f, 0.f, 0.f}, acc1 = {0.f, 0.f, 0.f, 0.f};
  const unsigned short* ar = att + (size_t)(tok0 + l16) * 1536 + quad * 8;
  const unsigned short* wr = wob + (size_t)(e0 + l16) * 1536 + quad * 8;
#pragma unroll 4
  for (int s = 0; s < 24; ++s) {
    v8s a0 = *(const v8s*)(ar + (2 * s) * 32);
    v8s b0 = *(const v8s*)(wr + (2 * s) * 32);
    v8s a1 = *(const v8s*)(ar + (2 * s + 1) * 32);
    v8s b1 = *(const v8s*)(wr + (2 * s + 1) * 32);
    acc0 = MFMA16(a0, b0, acc0);
    acc1 = MFMA16(a1, b1, acc1);
  }
#pragma unroll
  for (int r = 0; r < 4; ++r)
    out[(size_t)(tok0 + quad * 4 + r) * 64 + e0 + l16] = acc0[r] + acc1[r];
}

// ---------------------------------------------------------------------------
extern "C" void kernel_launch(void* const* d_in, const int* in_sizes, int n_in,
                              void* d_out, int out_size, void* d_ws,
                              size_t ws_size, hipStream_t stream) {
  const float* q  = (const float*)d_in[0];
  const float* Wq = (const float*)d_in[1];
  const float* Wk = (const float*)d_in[2];
  const float* Wv = (const float*)d_in[3];
  const float* Wo = (const float*)d_in[4];
  float* out = (float*)d_out;

  // workspace layout (bytes):
  //   qh  bf16 [2,12,2048,128]  @ 0           (Q pre-scaled by SCALE2)
  //   kh  bf16 [2,12,2048,128]  @ 12582912
  //   vtf bf16 [24][32][4][4][64][8] @ 25165824   (fragment-linear V)
  //   att bf16 [2,2048,1536]    @ 37748736
  //   cos_t f32 [2048,64]       @ 50331648  (dead after proj_rope; attn's
  //        qb==0 blocks overwrite with Wo bf16 = wob, read by outproj)
  //   sin_t f32 [2048,64]       @ 50855936   (total 51380224)
  unsigned short* ws = (unsigned short*)d_ws;
  unsigned short* qh  = ws;
  unsigned short* kh  = ws + 6291456;
  unsigned short* vtf = ws + 12582912;
  unsigned short* att = ws + 18874368;
  float* cos_t = (float*)((char*)d_ws + 50331648);
  float* sin_t = cos_t + 131072;
  unsigned short* wob = (unsigned short*)cos_t;   // reuse after proj_rope

  rope_table<<<512, 256, 0, stream>>>(cos_t, sin_t);
  proj_rope<<<dim3(64, 72), 256, 0, stream>>>(q, Wq, Wk, Wv, cos_t, sin_t,
                                              qh, kh, vtf);
  attn<<<dim3(24, 16), 512, 0, stream>>>(qh, kh, vtf, att, Wo, wob);
  outproj<<<256, 256, 0, stream>>>(att, wob, out);
}

// Round 5
// 181.241 us; speedup vs baseline: 2.3416x; 1.0154x over previous
//
#include <hip/hip_runtime.h>
#include <stdint.h>

// ---------------------------------------------------------------------------
// Problem: B=2, S=2048, E=64, H=12, D=128, inner=1536
// Pipeline: [rope table] -> [QKV proj + RoPE -> bf16 (Q pre-scaled)] ->
//           [causal flash attn, split-K within block, K+V in LDS,
//            32x32 MFMA, no-max softmax, + Wo cast in light blocks] ->
//           [output proj]
// ---------------------------------------------------------------------------

typedef short v8s __attribute__((ext_vector_type(8)));    // 8 x bf16
typedef unsigned int v4u __attribute__((ext_vector_type(4)));
typedef float v4f __attribute__((ext_vector_type(4)));
typedef float v16f __attribute__((ext_vector_type(16)));

#define MFMA16(a, b, c) __builtin_amdgcn_mfma_f32_16x16x32_bf16(a, b, c, 0, 0, 0)
#define MFMA32(a, b, c) __builtin_amdgcn_mfma_f32_32x32x16_bf16(a, b, c, 0, 0, 0)

#if __has_builtin(__builtin_amdgcn_exp2f)
#define EXP2(x) __builtin_amdgcn_exp2f(x)
#else
#define EXP2(x) exp2f(x)
#endif

// 1/sqrt(128) * log2(e): folded into Q at projection time
#define SCALE2 (0.08838834764831845f * 1.4426950408889634f)

__device__ __forceinline__ unsigned short f2bf(float f) {
  uint32_t u = __builtin_bit_cast(uint32_t, f);
  u += 0x7FFFu + ((u >> 16) & 1u);   // round-to-nearest-even
  return (unsigned short)(u >> 16);
}

// pack two fp32 -> bf16x2 word (round-half-up) via 2 adds + v_perm_b32
__device__ __forceinline__ uint32_t packbf(float lo, float hi) {
  return __builtin_amdgcn_perm(__builtin_bit_cast(uint32_t, hi) + 0x8000u,
                               __builtin_bit_cast(uint32_t, lo) + 0x8000u,
                               0x07060302u);
}

__device__ __forceinline__ v16f zero16() {
  v16f z;
#pragma unroll
  for (int i = 0; i < 16; ++i) z[i] = 0.f;
  return z;
}

// async global->LDS, 16 B per lane. LDS dst must be wave-uniform base + lane*16.
__device__ __forceinline__ void gl_lds16(const unsigned short* g, unsigned short* l) {
  __builtin_amdgcn_global_load_lds(
      (const __attribute__((address_space(1))) uint32_t*)g,
      (__attribute__((address_space(3))) uint32_t*)l, 16, 0, 0);
}

// ---------------------------------------------------------------------------
// Kernel 0: rope cos/sin table [S=2048][half=64]
// ---------------------------------------------------------------------------
__global__ __launch_bounds__(256) void rope_table(float* __restrict__ cos_t,
                                                  float* __restrict__ sin_t) {
  int idx = blockIdx.x * 256 + threadIdx.x;
  if (idx >= 2048 * 64) return;
  int s = idx >> 6, f = idx & 63;
  // 10000^(-f/64) = exp2(-f * log2(10000)/64)
  float inv = exp2f((float)f * -0.20762050593046014f);
  float ang = (float)s * inv;
  float si, co;
  sincosf(ang, &si, &co);
  cos_t[idx] = co;
  sin_t[idx] = si;
}

// ---------------------------------------------------------------------------
// Kernel 1: QKV projection + RoPE + bf16 cast, LDS-staged coalesced output.
// Q additionally scaled by SCALE2 (rotation commutes with scaling).
// qh/kh: bf16 [B,H,S,D].
// V written FRAGMENT-LINEAR for attn's LDS-staged PV reads:
//   vtf[bh][kt=tok/64][G=chunk/2 (4)][dt=d/32 (4)][lane=hh*32+(d&31) (64)][8 keys]
//   where chunk=(tok%64)/8, hh=chunk&1, G=chunk>>1.
//   Each (G,dt) block = 64 lanes x 16B contiguous -> trivial gl_lds16 copy and
//   conflict-free ds_read_b128 fragments.
// ---------------------------------------------------------------------------
__global__ __launch_bounds__(256) void proj_rope(
    const float* __restrict__ x, const float* __restrict__ Wq,
    const float* __restrict__ Wk, const float* __restrict__ Wv,
    const float* __restrict__ cos_t, const float* __restrict__ sin_t,
    unsigned short* __restrict__ qh, unsigned short* __restrict__ kh,
    unsigned short* __restrict__ vt) {
  const int wave = threadIdx.x >> 6, lane = threadIdx.x & 63;
  const int l16 = lane & 15, quad = lane >> 4;
  const int by = blockIdx.y;
  const int o_base = by * 64 + wave * 16;
  const int mat = o_base / 1536;                    // 0=q 1=k 2=v (block-uniform)
  const int inner0 = o_base % 1536;
  const int d0w = inner0 & 127;
  const float* Wsrc = (mat == 0) ? Wq : ((mat == 1) ? Wk : Wv);
  const float qscale = (mat == 0) ? SCALE2 : 1.0f;

  __shared__ __align__(16) unsigned short Lt[64][72];

  v8s wb[2];
  {
    const float* wr = Wsrc + (size_t)(inner0 + l16) * 64 + quad * 8;
#pragma unroll
    for (int s = 0; s < 2; ++s) {
      float4 a = *(const float4*)(wr + s * 32);
      float4 b = *(const float4*)(wr + s * 32 + 4);
      v8s t;
      t[0] = (short)f2bf(a.x); t[1] = (short)f2bf(a.y);
      t[2] = (short)f2bf(a.z); t[3] = (short)f2bf(a.w);
      t[4] = (short)f2bf(b.x); t[5] = (short)f2bf(b.y);
      t[6] = (short)f2bf(b.z); t[7] = (short)f2bf(b.w);
      wb[s] = t;
    }
  }

  const int d = d0w + l16;
  const int half = d >> 1;

#pragma unroll
  for (int i = 0; i < 4; ++i) {
    const int tok0 = blockIdx.x * 64 + i * 16;
    const float* xr = x + (size_t)(tok0 + l16) * 64 + quad * 8;
    v8s xa[2];
#pragma unroll
    for (int s = 0; s < 2; ++s) {
      float4 a = *(const float4*)(xr + s * 32);
      float4 b = *(const float4*)(xr + s * 32 + 4);
      v8s t;
      t[0] = (short)f2bf(a.x); t[1] = (short)f2bf(a.y);
      t[2] = (short)f2bf(a.z); t[3] = (short)f2bf(a.w);
      t[4] = (short)f2bf(b.x); t[5] = (short)f2bf(b.y);
      t[6] = (short)f2bf(b.z); t[7] = (short)f2bf(b.w);
      xa[s] = t;
    }
    v4f acc = {0.f, 0.f, 0.f, 0.f};
    acc = MFMA16(xa[0], wb[0], acc);
    acc = MFMA16(xa[1], wb[1], acc);

    if (mat < 2) {
#pragma unroll
      for (int r = 0; r < 4; ++r) {
        int sidx = (tok0 + quad * 4 + r) & 2047;
        float val = acc[r];
        float prt = __shfl_xor(val, 1);   // pair partner (d^1), same token
        float co = cos_t[sidx * 64 + half];
        float si = sin_t[sidx * 64 + half];
        float rot = ((d & 1) == 0) ? (val * co - prt * si)
                                   : (prt * si + val * co);
        Lt[i * 16 + quad * 4 + r][wave * 16 + l16] = f2bf(rot * qscale);
      }
    } else {
#pragma unroll
      for (int r = 0; r < 4; ++r)
        Lt[wave * 16 + l16][i * 16 + quad * 4 + r] = f2bf(acc[r]);
    }
  }
  __syncthreads();

  // cooperative b128 coalesced readout
  const int matb = (by * 64) / 1536;
  const int innerb = (by * 64) % 1536;
  const int hb = innerb >> 7;
  const int d0b = innerb & 127;
  const int b = (blockIdx.x * 64) >> 11;
  const int tokbase = (blockIdx.x * 64) & 2047;
#pragma unroll
  for (int jj = 0; jj < 2; ++jj) {
    int cid = jj * 256 + threadIdx.x;
    int outer = cid >> 3, ic = cid & 7;
    v8s val = *(const v8s*)&Lt[outer][ic * 8];
    if (matb < 2) {
      unsigned short* dst = (matb == 0 ? qh : kh) +
          (((size_t)(b * 12 + hb)) * 2048 + tokbase + outer) * 128 + d0b + ic * 8;
      *(v8s*)dst = val;
    } else {
      // fragment-linear vtf store: Lt[outer][ic*8+e] = V^T[d0b+outer][tokbase+ic*8+e]
      const int kt = tokbase >> 6;
      const int G = ic >> 1, hhb = ic & 1;
      const int dd = d0b + outer;
      unsigned short* dst = vt +
          ((((((size_t)(b * 12 + hb)) * 32 + kt) * 4 + G) * 4 + (dd >> 5)) * 64 +
           hhb * 32 + (dd & 31)) * 8;
      *(v8s*)dst = val;
    }
  }
}

// ---------------------------------------------------------------------------
// Kernel 2: causal flash attention, SPLIT-K within block, K+V both in LDS.
// R4 post-mortem: V "direct-to-register" loads moved 128KB/step through the
// CU L2 port but only 32KB was unique (4 row-waves re-load the same V tile;
// registers can't broadcast across waves) -> the critical CU was L2-PORT-
// bound at ~9200cy/step. Fix: stage V in LDS next to K (fragment-linear vtf
// makes gl_lds16 a contiguous copy; PV fragments become conflict-free
// ds_read_b128). Per-step CU traffic: 160KB L2 -> 64KB L2 + 256KB LDS
// (~85 B/cy -> ~3000cy/step ceiling). LDS = 2 herds x dbuf x (16K K+16K V)
// = 128KB dynamic -> 1 block/CU (occupancy ~8 waves/CU BY DESIGN; we are
// port-bound, not latency-bound). VGPR drops (V frags now transient).
// Queue balance (1 block/CU => per-CU QUEUES): 1-D grid where n and n+256
// co-locate under both linear and XCD-round-robin dispatch (256%8==0):
// primaries n<256 = qb 15..5 descending, secondaries = qb 0..5 ascending ->
// paired CU queues sum to exactly 17 step-units, singles <=11. XCD pinning
// n%8==bh%8 preserved for all cases.
// Split-K: waves 0-3 (rows rg*32) do key-tiles [0,qb+1), waves 4-7 do
// [qb+1,2qb+2). No running max -> exact combine O=Olo+Oup, l=llo+lup.
// qb==0 blocks (lightest) also cast Wo->bf16 into the dead cos-table region.
// ---------------------------------------------------------------------------
__global__ __launch_bounds__(512, 2) void attn(
    const unsigned short* __restrict__ qh, const unsigned short* __restrict__ kh,
    const unsigned short* __restrict__ vtf, unsigned short* __restrict__ att,
    const float* __restrict__ Wo, unsigned short* __restrict__ wob) {
  extern __shared__ __align__(16) unsigned short SH[];
  unsigned short* KSH = SH;            // 4 slots x 8192 shorts (K)  [64 KB]
  unsigned short* VSH = SH + 32768;    // 4 slots x 8192 shorts (V)  [64 KB]

  // ---- balanced 1-D decode (see header comment)
  const int n = blockIdx.x;
  int qb, bh;
  if (n < 240)      { qb = 15 - n / 24; bh = n % 24; }
  else if (n < 256) { qb = 5;           bh = n - 240; }
  else if (n < 376) { int r = n - 256; qb = r / 24; bh = r % 24; }
  else              { qb = 5;           bh = 16 + (n - 376); }

  const int t = threadIdx.x;
  const int lane = t & 63;
  const int l31 = lane & 31, hh = lane >> 5;
  const int w = t >> 6;                          // 8 waves
  const int rg = w & 3, kherd = w >> 2;          // row-group / key-range half
  const int r0w = qb * 128 + rg * 32;
  const int qrow = r0w + l31;
  const int rowmax = r0w + 31;

  const unsigned short* Qb = qh + (size_t)bh * 2048 * 128;
  const unsigned short* Kb = kh + (size_t)bh * 2048 * 128;
  const unsigned short* Vb = vtf + (size_t)bh * 262144;   // 32*4*4*64*8

  // Q fragments (serve as MFMA B-operand): Q[qrow][ks*16 + hh*8 + j]
  v8s qa[8];
  {
    const unsigned short* qr = Qb + (size_t)qrow * 128 + hh * 8;
#pragma unroll
    for (int ks = 0; ks < 8; ++ks) qa[ks] = *(const v8s*)(qr + ks * 16);
  }

  // staging offsets: K swizzle chunk (key, c) holds global d-chunk c^(key&15);
  // V tile is already fragment-linear -> identity copy.
  int offK[2];
#pragma unroll
  for (int i2 = 0; i2 < 2; ++i2) {
    int flat = i2 * 512 + t;
    int kr = flat >> 4, kc = flat & 15;
    offK[i2] = kr * 128 + ((kc ^ (kr & 15)) << 3);
  }
  auto stageK = [&](int ktile, int slot) {
    const unsigned short* kg = Kb + ((size_t)(ktile << 6)) * 128;
    unsigned short* db = &KSH[slot * 8192];
#pragma unroll
    for (int i2 = 0; i2 < 2; ++i2)
      gl_lds16(kg + offK[i2], db + ((i2 * 512 + t) << 3));
  };
  auto stageV = [&](int ktile, int slot) {
    const unsigned short* vg = Vb + (size_t)ktile * 8192;
    unsigned short* db = &VSH[slot * 8192];
#pragma unroll
    for (int i2 = 0; i2 < 2; ++i2)
      gl_lds16(vg + ((i2 * 512 + t) << 3), db + ((i2 * 512 + t) << 3));
  };

  v16f O[4];
#pragma unroll
  for (int i = 0; i < 4; ++i) O[i] = zero16();
  float lsum = 0.f;

  const int NS = qb + 1;
  stageK(0, 0); stageV(0, 0);            // lower range, buf 0
  stageK(qb + 1, 2); stageV(qb + 1, 2);  // upper range, buf 0
  asm volatile("s_waitcnt vmcnt(0)" ::: "memory");

  for (int i = 0; i < NS; ++i) {
    __builtin_amdgcn_s_barrier();          // publishes both step-i tile pairs
    __builtin_amdgcn_sched_barrier(0);
    const int kt = kherd ? (qb + 1 + i) : i;
    const int key0 = kt << 6;
    const bool active = key0 <= rowmax;
    const bool hi = (key0 + 32) <= rowmax;

    // ---- next step's K+V DMA for both ranges (issued first; covered by compute)
    if (i + 1 < NS) {
      stageK(i + 1, (i + 1) & 1);
      stageV(i + 1, (i + 1) & 1);
      stageK(qb + 2 + i, 2 + ((i + 1) & 1));
      stageV(qb + 2 + i, 2 + ((i + 1) & 1));
    }
    __builtin_amdgcn_sched_barrier(0);

    if (active) {
      const unsigned short* Kl = &KSH[(kherd * 2 + (i & 1)) * 8192];
      const unsigned short* Vl = &VSH[(kherd * 2 + (i & 1)) * 8192];
      const bool mask0 = (key0 + 31) > r0w;
      const bool mask1 = (key0 + 63) > r0w;

      // ---- softpack: S^T half-tile -> packed bf16 P-words + lsum
      auto softpack = [&](const v16f& SS, const v16f& ST, int kh2, bool needmask,
                          uint32_t* W) {
#pragma unroll
        for (int m = 0; m < 8; ++m) {
          float pa = EXP2(SS[2 * m] + ST[2 * m]);
          float pb = EXP2(SS[2 * m + 1] + ST[2 * m + 1]);
          if (needmask) {
            int keyb = key0 + kh2 * 32 + 2 * (m & 1) + 8 * (m >> 1) + 4 * hh;
            pa = (keyb <= qrow) ? pa : 0.f;
            pb = (keyb + 1 <= qrow) ? pb : 0.f;
          }
          lsum += pa + pb;
          W[m] = packbf(pa, pb);
        }
      };
      // ---- pv: build B-operand P frags (word swap across lane^32), mult V^T
      auto pvhalf = [&](const uint32_t* W, int kh2) {
        uint32_t r0 = __shfl_xor(hh ? W[0] : W[2], 32);
        uint32_t r1 = __shfl_xor(hh ? W[1] : W[3], 32);
        uint32_t r2 = __shfl_xor(hh ? W[4] : W[6], 32);
        uint32_t r3 = __shfl_xor(hh ? W[5] : W[7], 32);
#pragma unroll
        for (int gl = 0; gl < 2; ++gl) {
          const int g = kh2 * 2 + gl;
          if (key0 + g * 16 > rowmax) continue;   // wave-uniform skip
          uint32_t rA = gl ? r2 : r0, rB = gl ? r3 : r1;
          v4u fw;
          fw.x = hh ? rA : W[4 * gl];
          fw.y = hh ? rB : W[4 * gl + 1];
          fw.z = hh ? W[4 * gl + 2] : rA;
          fw.w = hh ? W[4 * gl + 3] : rB;
          v8s pfrag = __builtin_bit_cast(v8s, fw);
          __builtin_amdgcn_s_setprio(1);
#pragma unroll
          for (int dt = 0; dt < 4; ++dt) {
            v8s va = *(const v8s*)(Vl + (((g * 4 + dt) * 64 + lane) << 3));
            O[dt] = MFMA32(va, pfrag, O[dt]);
          }
          __builtin_amdgcn_s_setprio(0);
        }
      };

      // ---- S^T = K·Q^T lower 32 keys (two independent 4-deep chains)
      v16f Sa = zero16(), Sb = zero16();
      __builtin_amdgcn_s_setprio(1);
#pragma unroll
      for (int ks = 0; ks < 8; ks += 2) {
        v8s ka0 = *(const v8s*)(
            Kl + ((l31 * 16 + ((2 * ks + hh) ^ (l31 & 15))) << 3));
        v8s ka1 = *(const v8s*)(
            Kl + ((l31 * 16 + ((2 * ks + 2 + hh) ^ (l31 & 15))) << 3));
        Sa = MFMA32(ka0, qa[ks], Sa);
        Sb = MFMA32(ka1, qa[ks + 1], Sb);
      }
      __builtin_amdgcn_s_setprio(0);
      uint32_t W0[8];
      softpack(Sa, Sb, 0, mask0, W0);
      pvhalf(W0, 0);

      if (hi) {
        v16f Sc = zero16(), Sd = zero16();
        __builtin_amdgcn_s_setprio(1);
#pragma unroll
        for (int ks = 0; ks < 8; ks += 2) {
          v8s ka0 = *(const v8s*)(
              Kl + (((32 + l31) * 16 + ((2 * ks + hh) ^ (l31 & 15))) << 3));
          v8s ka1 = *(const v8s*)(
              Kl + (((32 + l31) * 16 + ((2 * ks + 2 + hh) ^ (l31 & 15))) << 3));
          Sc = MFMA32(ka0, qa[ks], Sc);
          Sd = MFMA32(ka1, qa[ks + 1], Sd);
        }
        __builtin_amdgcn_s_setprio(0);
        uint32_t W1[8];
        softpack(Sc, Sd, 1, mask1, W1);
        pvhalf(W1, 1);
      }
    }
    // staged DMA must retire before next barrier publishes the buffers
    asm volatile("s_waitcnt vmcnt(0)" ::: "memory");
  }

  // ---- split-K reduce, phased over the 64KB K area (dead after loop):
  //   (1) upper waves dump O fp32 (XOR-swizzled float4), (2) lower accumulate
  //   into registers, (3) upper dump lsum, (4) lower normalize + store att.
  __syncthreads();                        // all K/V reads done; LDS reusable
  float* Ored = (float*)KSH;              // [rg][l31][128] XOR-swizzled
  if (kherd == 1) {
    float* baseO = Ored + rg * 4096 + l31 * 128;
#pragma unroll
    for (int dt = 0; dt < 4; ++dt)
#pragma unroll
      for (int pr = 0; pr < 4; ++pr) {
        float4 v;
        v.x = O[dt][4 * pr + 0]; v.y = O[dt][4 * pr + 1];
        v.z = O[dt][4 * pr + 2]; v.w = O[dt][4 * pr + 3];
        *(float4*)(baseO + dt * 32 + (((2 * pr + hh) ^ (l31 & 7)) << 2)) = v;
      }
  }
  __syncthreads();
  if (kherd == 0) {
    const float* baseO = Ored + rg * 4096 + l31 * 128;
#pragma unroll
    for (int dt = 0; dt < 4; ++dt)
#pragma unroll
      for (int pr = 0; pr < 4; ++pr) {
        float4 v = *(const float4*)(
            baseO + dt * 32 + (((2 * pr + hh) ^ (l31 & 7)) << 2));
        O[dt][4 * pr + 0] += v.x;
        O[dt][4 * pr + 1] += v.y;
        O[dt][4 * pr + 2] += v.z;
        O[dt][4 * pr + 3] += v.w;
      }
  }
  __syncthreads();
  if (kherd == 1) Ored[rg * 64 + lane] = lsum;
  __syncthreads();
  if (kherd == 0) {
    const float lt = lsum + Ored[rg * 64 + lane];
    const float tot = lt + __shfl_xor(lt, 32);
    const float inv = 1.0f / tot;
    const int b = bh / 12, hq = bh % 12;
    unsigned short* arow = att + ((size_t)b * 2048 + qrow) * 1536 + hq * 128;
#pragma unroll
    for (int dt = 0; dt < 4; ++dt) {
#pragma unroll
      for (int pr = 0; pr < 4; ++pr) {
        float a0 = O[dt][4 * pr + 0] * inv;
        float a1 = O[dt][4 * pr + 1] * inv;
        float a2 = O[dt][4 * pr + 2] * inv;
        float a3 = O[dt][4 * pr + 3] * inv;
        uint2 uu;
        uu.x = packbf(a0, a1);
        uu.y = packbf(a2, a3);
        *(uint2*)(arow + dt * 32 + 8 * pr + 4 * hh) = uu;
      }
    }
  }

  // ---- lightest blocks also cast Wo -> bf16 (cos table region is dead now)
  if (qb == 0) {
    const int base = bh * 4096;
#pragma unroll
    for (int i = 0; i < 8; ++i)
      wob[base + i * 512 + t] = f2bf(Wo[base + i * 512 + t]);
  }
}

// ---------------------------------------------------------------------------
// Kernel 3: output projection out[tok][e] = sum_i att[tok][i] * Wob[e][i]
// ---------------------------------------------------------------------------
__global__ __launch_bounds__(256) void outproj(
    const unsigned short* __restrict__ att, const unsigned short* __restrict__ wob,
    float* __restrict__ out) {
  const int wave = threadIdx.x >> 6, lane = threadIdx.x & 63;
  const int l16 = lane & 15, quad = lane >> 4;
  const int tok0 = blockIdx.x * 16;
  const int e0 = wave * 16;

  v4f acc0 = {0.f, 0.f, 0.f, 0.f}, acc1 = {0.f, 0.f, 0.f, 0.f};
  const unsigned short* ar = att + (size_t)(tok0 + l16) * 1536 + quad * 8;
  const unsigned short* wr = wob + (size_t)(e0 + l16) * 1536 + quad * 8;
#pragma unroll 4
  for (int s = 0; s < 24; ++s) {
    v8s a0 = *(const v8s*)(ar + (2 * s) * 32);
    v8s b0 = *(const v8s*)(wr + (2 * s) * 32);
    v8s a1 = *(const v8s*)(ar + (2 * s + 1) * 32);
    v8s b1 = *(const v8s*)(wr + (2 * s + 1) * 32);
    acc0 = MFMA16(a0, b0, acc0);
    acc1 = MFMA16(a1, b1, acc1);
  }
#pragma unroll
  for (int r = 0; r < 4; ++r)
    out[(size_t)(tok0 + quad * 4 + r) * 64 + e0 + l16] = acc0[r] + acc1[r];
}

// ---------------------------------------------------------------------------
extern "C" void kernel_launch(void* const* d_in, const int* in_sizes, int n_in,
                              void* d_out, int out_size, void* d_ws,
                              size_t ws_size, hipStream_t stream) {
  const float* q  = (const float*)d_in[0];
  const float* Wq = (const float*)d_in[1];
  const float* Wk = (const float*)d_in[2];
  const float* Wv = (const float*)d_in[3];
  const float* Wo = (const float*)d_in[4];
  float* out = (float*)d_out;

  // workspace layout (bytes):
  //   qh  bf16 [2,12,2048,128]  @ 0           (Q pre-scaled by SCALE2)
  //   kh  bf16 [2,12,2048,128]  @ 12582912
  //   vtf bf16 [24][32][4][4][64][8] @ 25165824   (fragment-linear V)
  //   att bf16 [2,2048,1536]    @ 37748736
  //   cos_t f32 [2048,64]       @ 50331648  (dead after proj_rope; attn's
  //        qb==0 blocks overwrite with Wo bf16 = wob, read by outproj)
  //   sin_t f32 [2048,64]       @ 50855936   (total 51380224)
  unsigned short* ws = (unsigned short*)d_ws;
  unsigned short* qh  = ws;
  unsigned short* kh  = ws + 6291456;
  unsigned short* vtf = ws + 12582912;
  unsigned short* att = ws + 18874368;
  float* cos_t = (float*)((char*)d_ws + 50331648);
  float* sin_t = cos_t + 131072;
  unsigned short* wob = (unsigned short*)cos_t;   // reuse after proj_rope

  // attn needs 128 KB dynamic LDS (gfx950 allows 160 KB with opt-in)
  hipFuncSetAttribute((const void*)attn,
                      hipFuncAttributeMaxDynamicSharedMemorySize, 131072);

  rope_table<<<512, 256, 0, stream>>>(cos_t, sin_t);
  proj_rope<<<dim3(64, 72), 256, 0, stream>>>(q, Wq, Wk, Wv, cos_t, sin_t,
                                              qh, kh, vtf);
  attn<<<dim3(384), 512, 131072, stream>>>(qh, kh, vtf, att, Wo, wob);
  outproj<<<256, 256, 0, stream>>>(att, wob, out);
}